// Round 7
// baseline (206.019 us; speedup 1.0000x reference)
//
#include <hip/hip_runtime.h>
#include <hip/hip_bf16.h>

// ---------------------------------------------------------------------------
// GCN layer: out = D^{-1/2} (A_set + I) D^{-1/2} @ (x @ W) + bias
// Pipeline (4 dispatches, each a SEPARATE named kernel for per-phase
// profiling -- r6 lesson: fused_front/fused_mid were never visible in top-5
// and hid ~110us):
//   adj_ell: 128 blocks x 64 nodes, row-bitmask in LDS (64KB). Each block
//     scans the full edge list (L2-broadcast), ds_or LDS atomics (replaces
//     512K device-scope atomicOr -> memory-side RMW, est 30-50us), then
//     builds ELL rows straight from LDS. Kills: mask memset dispatch, 8MB
//     mask write, 8MB mask read.
//   prep: cast x->bf16 | transpose W | zero Hs pad row + dinv[M].
//   gemm: 128x128 MFMA BK=64, XOR-swizzled B staging (r6 structure).
//   spmm: wave=node, full-D row/entry, EXPLICIT depth-8 prefetch pipeline
//     (r5/r6 lesson: latency-invariant to locality, VGPR_Count=32 shows
//     compiler capped MLP at ~2; pf[8] forces 8 outstanding 1KB gathers).
// ---------------------------------------------------------------------------

#define ELL_STRIDE 128

typedef __attribute__((ext_vector_type(8))) short bf16x8;
typedef __attribute__((ext_vector_type(4))) float f32x4;

__device__ __forceinline__ unsigned short f2bf(float f) {
  unsigned u = __float_as_uint(f);
  u = (u + 0x7fff + ((u >> 16) & 1)) >> 16;  // RNE
  return (unsigned short)u;
}
__device__ __forceinline__ float bflo(unsigned u) {
  return __uint_as_float(u << 16);
}
__device__ __forceinline__ float bfhi(unsigned u) {
  return __uint_as_float(u & 0xffff0000u);
}

// ---- adj_ell: block b owns nodes [b*64, b*64+64). 64KB LDS bitmask.
// Phase 1: zero LDS. Phase 2: scan all edges; endpoints in range set bits
// via LDS atomicOr (ds_or, no return, cheap). Phase 3: per wave, 8 nodes:
// popc + 64-lane prefix scan + emit ELL entries (+self, pads), deg, dinv.
// Entry order within a row is irrelevant (spmm sums a set).
__global__ __launch_bounds__(512) void adj_ell_kernel(
    const int* __restrict__ ei, unsigned short* __restrict__ ell,
    int* __restrict__ deg, float* __restrict__ dinv,
    int n_nodes, int n_edges, int words) {
  __shared__ unsigned sm[64 * 256];  // 64 nodes x 256 words = 64KB

  const int tid = threadIdx.x;
  const int base = blockIdx.x << 6;

  // zero
#pragma unroll
  for (int t = tid; t < 64 * 256; t += 512) sm[t] = 0u;
  __syncthreads();

  // edge scan: int4-vectorized, both endpoint directions
  {
    const int4* __restrict__ eu4 = (const int4*)ei;
    const int4* __restrict__ ev4 = (const int4*)(ei + n_edges);
    const int nq = n_edges >> 2;
    for (int t = tid; t < nq; t += 512) {
      const int4 u4 = eu4[t];
      const int4 v4 = ev4[t];
#define PROC(uu, vv)                                                        \
  {                                                                         \
    const int u_ = (uu), v_ = (vv);                                         \
    if ((unsigned)(u_ - base) < 64u)                                        \
      atomicOr(&sm[((u_ - base) << 8) + (v_ >> 5)], 1u << (v_ & 31));       \
    if ((unsigned)(v_ - base) < 64u)                                        \
      atomicOr(&sm[((v_ - base) << 8) + (u_ >> 5)], 1u << (u_ & 31));       \
  }
      PROC(u4.x, v4.x) PROC(u4.y, v4.y) PROC(u4.z, v4.z) PROC(u4.w, v4.w)
#undef PROC
    }
  }
  __syncthreads();

  // ELL build: wave w -> nodes base + w*8 .. +8
  {
    const int wave = tid >> 6, lane = tid & 63;
    for (int s = 0; s < 8; ++s) {
      const int nl = wave * 8 + s;
      const int node = base + nl;
      unsigned w[4];
      int cnt = 0;
#pragma unroll
      for (int j = 0; j < 4; ++j) {
        w[j] = sm[(nl << 8) + lane + j * 64];
        cnt += __popc(w[j]);
      }
      int x = cnt;
#pragma unroll
      for (int d = 1; d < 64; d <<= 1) {
        int y = __shfl_up(x, d, 64);
        if (lane >= d) x += y;
      }
      int pos = x - cnt;                        // exclusive prefix
      const int total = __shfl(x, 63, 64);      // row popcount
      unsigned short* __restrict__ out = ell + (size_t)node * ELL_STRIDE;
#pragma unroll
      for (int j = 0; j < 4; ++j) {
        unsigned bits = w[j];
        const int wj = lane + j * 64;
        while (bits) {
          const int b = __builtin_ctz(bits);
          bits &= bits - 1;
          if (pos < ELL_STRIDE) out[pos] = (unsigned short)((wj << 5) + b);
          ++pos;
        }
      }
      // self entry at [total], pads (index n_nodes -> dinv 0, zero row)
      for (int p = total + lane; p < ELL_STRIDE; p += 64)
        out[p] = (unsigned short)(p == total ? node : n_nodes);
      if (lane == 0) {
        const int dd = total + 1;
        deg[node] = dd < ELL_STRIDE ? dd : ELL_STRIDE;
        dinv[node] = rsqrtf((float)total + 1.0f);
      }
    }
  }
}

// ---- prep: [0,cb): cast x->bf16   [cb,cb+tb): transpose W   [last]: pads
__global__ __launch_bounds__(256) void prep_kernel(
    const float* __restrict__ x, unsigned short* __restrict__ xb, int n4,
    const float* __restrict__ W, unsigned short* __restrict__ Wt, int K, int N,
    unsigned short* __restrict__ Hs, float* __restrict__ dinv, int n_nodes,
    int cast_blocks, int tr_blocks) {
  const int bid = blockIdx.x;
  if (bid < cast_blocks) {
    const int t = bid * 256 + threadIdx.x;
    if (t < n4) {
      float4 v = ((const float4*)x)[t];
      ushort4 o;
      o.x = f2bf(v.x); o.y = f2bf(v.y); o.z = f2bf(v.z); o.w = f2bf(v.w);
      ((ushort4*)xb)[t] = o;
    }
    return;
  }
  if (bid < cast_blocks + tr_blocks) {
    // transpose+cast: W[K][N] fp32 -> Wt[N][K] bf16, 32x32 tiles
    __shared__ float tile[32][33];
    const int b = bid - cast_blocks;
    const int bx = b & ((N >> 5) - 1);
    const int by = b >> (31 - __builtin_clz(N >> 5));
    const int tx = threadIdx.x & 31;
    const int ty = threadIdx.x >> 5;  // 0..7
#pragma unroll
    for (int r = 0; r < 4; ++r)
      tile[ty + 8 * r][tx] = W[(size_t)(by * 32 + ty + 8 * r) * N + bx * 32 + tx];
    __syncthreads();
#pragma unroll
    for (int r = 0; r < 4; ++r)
      Wt[(size_t)(bx * 32 + ty + 8 * r) * K + by * 32 + tx] =
          f2bf(tile[tx][ty + 8 * r]);
    return;
  }
  // zero the ELL pad row Hs[n_nodes][:] and its scale dinv[n_nodes]
  {
    const int t = threadIdx.x;
    if (t < (N >> 1)) ((unsigned*)(Hs + (size_t)n_nodes * N))[t] = 0;
    if (t == 0) dinv[n_nodes] = 0.f;
  }
}

// ---- gemm: 128x128 tile, BK=64, 4 waves 2x2, XOR-swizzled B staging.
__global__ __launch_bounds__(256) void gemm_kernel(
    const unsigned short* __restrict__ xb,  // [M][K] bf16
    const unsigned short* __restrict__ Wt,  // [N][K] bf16
    unsigned short* __restrict__ Hs,        // [M+1][N] bf16 (unscaled)
    int M, int N, int K, int nbx_sh) {
  // A slot s (0..1023): row=s&127, kc=s>>7 -> xb[m0+row][k0+kc*8]
  // B slot s (0..1023): bn=s>>3, bk=(s&7)^(bn&7)  (XOR source pre-swizzle:
  //   stride-128B fragment read spans all 8 bank-quads; source swizzled
  //   because global_load_lds forces a linear LDS dest).
  __shared__ unsigned short As[1024 * 8];
  __shared__ unsigned short Bs[1024 * 8];

  const int tid = threadIdx.x;
  const int bid = blockIdx.x;
  const int wave = tid >> 6;
  const int lane = tid & 63;
  const int q = lane >> 4;   // quad
  const int c = lane & 15;
  const int bx = bid & ((1 << nbx_sh) - 1);
  const int by = bid >> nbx_sh;
  const int m0 = by * 128;
  const int n0 = bx * 128;
  const int wr = wave >> 1, wc = wave & 1;

  f32x4 acc[4][4] = {};

  for (int k0 = 0; k0 < K; k0 += 64) {
#pragma unroll
    for (int t = 0; t < 4; ++t) {
      const int sbase = t * 256 + wave * 64;
      const int s = sbase + lane;
      const unsigned short* g =
          xb + (size_t)(m0 + (s & 127)) * K + k0 + (s >> 7) * 8;
      __builtin_amdgcn_global_load_lds(
          (const __attribute__((address_space(1))) void*)g,
          (__attribute__((address_space(3))) void*)(As + sbase * 8), 16, 0, 0);
    }
#pragma unroll
    for (int t = 0; t < 4; ++t) {
      const int sbase = t * 256 + wave * 64;
      const int s = sbase + lane;
      const int bn = s >> 3;
      const int bk = (s & 7) ^ (bn & 7);  // XOR-swizzled source (same 128B seg)
      const unsigned short* g =
          Wt + (size_t)(n0 + bn) * K + k0 + bk * 8;
      __builtin_amdgcn_global_load_lds(
          (const __attribute__((address_space(1))) void*)g,
          (__attribute__((address_space(3))) void*)(Bs + sbase * 8), 16, 0, 0);
    }
    __syncthreads();

#pragma unroll
    for (int kk = 0; kk < 2; ++kk) {
      bf16x8 a[4], b[4];
#pragma unroll
      for (int tm = 0; tm < 4; ++tm) {
        const int row = wr * 64 + tm * 16 + c;
        a[tm] = *(const bf16x8*)(As + (((kk * 4 + q) * 128) + row) * 8);
      }
#pragma unroll
      for (int tn = 0; tn < 4; ++tn) {
        const int n = wc * 64 + tn * 16 + c;
        b[tn] = *(const bf16x8*)(Bs + (n * 8 + ((kk * 4 + q) ^ (n & 7))) * 8);
      }
#pragma unroll
      for (int tm = 0; tm < 4; ++tm)
#pragma unroll
        for (int tn = 0; tn < 4; ++tn)
          acc[tm][tn] = __builtin_amdgcn_mfma_f32_16x16x32_bf16(
              a[tm], b[tn], acc[tm][tn], 0, 0, 0);
    }
    __syncthreads();
  }

  // C/D mapping: col=lane&15, row=quad*4+reg ; unscaled store
#pragma unroll
  for (int tm = 0; tm < 4; ++tm) {
#pragma unroll
    for (int r = 0; r < 4; ++r) {
      const int grow = m0 + wr * 64 + tm * 16 + q * 4 + r;
#pragma unroll
      for (int tn = 0; tn < 4; ++tn) {
        const int gcol = n0 + wc * 64 + tn * 16 + c;
        Hs[(size_t)grow * N + gcol] = f2bf(acc[tm][tn][r]);
      }
    }
  }
}

// ---- spmm: grid n/4 blocks, wave = one node, FULL D per entry, explicit
// depth-8 prefetch. 64 lanes x 16B = 1KB = one Hs row per entry. pf[8]/dj[8]
// statically indexed (rule-#20) force 8 outstanding gathers per wave (the
// compiler alone capped at ~2: VGPR_Count=32, VALUBusy 36%). ji padded to
// 136 entries pointing at the zero pad row so the pipeline overruns safely.
__global__ __launch_bounds__(256) void spmm_kernel(
    const unsigned short* __restrict__ ell, const int* __restrict__ deg,
    const float* __restrict__ dinv, const unsigned short* __restrict__ Hs,
    const float* __restrict__ bias, float* __restrict__ out, int n, int D) {
  __shared__ uint2 ji[4][ELL_STRIDE + 8];
  const int wave = threadIdx.x >> 6, lane = threadIdx.x & 63;
  const int i = blockIdx.x * 4 + wave;  // n divisible by 4
  const unsigned rowbytes = (unsigned)(D * 2);

  {  // stage (byte offset, dinv[j]) — 2 entries per lane; dinv 32KB -> L1
    const unsigned j0 = ell[(size_t)i * ELL_STRIDE + lane];
    const unsigned j1 = ell[(size_t)i * ELL_STRIDE + 64 + lane];
    ji[wave][lane] = make_uint2(j0 * rowbytes, __float_as_uint(dinv[j0]));
    ji[wave][64 + lane] = make_uint2(j1 * rowbytes, __float_as_uint(dinv[j1]));
    if (lane < 8)  // overrun pad: zero row, weight 0
      ji[wave][ELL_STRIDE + lane] = make_uint2((unsigned)n * rowbytes, 0u);
  }
  const int d = deg[i];            // includes the self entry
  const float di = dinv[i];
  const int kmax = (d + 7) & ~7;   // ELL pads cover the tail

  const char* __restrict__ hb = (const char*)(Hs + lane * 8);  // 16B/lane
  float acc[8] = {0.f, 0.f, 0.f, 0.f, 0.f, 0.f, 0.f, 0.f};

  uint4 pf[8];
  unsigned dj[8];
#pragma unroll
  for (int p = 0; p < 8; ++p) {
    const uint2 e = ji[wave][p];
    dj[p] = e.y;
    pf[p] = *(const uint4*)(hb + e.x);
  }
  for (int k = 0; k < kmax; k += 8) {
#pragma unroll
    for (int p = 0; p < 8; ++p) {
      const float djv = __uint_as_float(dj[p]);
      const uint4 hv = pf[p];
      acc[0] += djv * bflo(hv.x); acc[1] += djv * bfhi(hv.x);
      acc[2] += djv * bflo(hv.y); acc[3] += djv * bfhi(hv.y);
      acc[4] += djv * bflo(hv.z); acc[5] += djv * bfhi(hv.z);
      acc[6] += djv * bflo(hv.w); acc[7] += djv * bfhi(hv.w);
      const uint2 e = ji[wave][k + 8 + p];  // max 127+8 < 136
      dj[p] = e.y;
      pf[p] = *(const uint4*)(hb + e.x);
    }
  }

  const float4 b0 = *(const float4*)(bias + lane * 8);
  const float4 b1 = *(const float4*)(bias + lane * 8 + 4);
  float* op = out + (size_t)i * D + lane * 8;
  f32x4 o0, o1;
  o0.x = di * acc[0] + b0.x; o0.y = di * acc[1] + b0.y;
  o0.z = di * acc[2] + b0.z; o0.w = di * acc[3] + b0.w;
  o1.x = di * acc[4] + b1.x; o1.y = di * acc[5] + b1.y;
  o1.z = di * acc[6] + b1.z; o1.w = di * acc[7] + b1.w;
  __builtin_nontemporal_store(o0, (f32x4*)op);
  __builtin_nontemporal_store(o1, (f32x4*)(op + 4));
}

extern "C" void kernel_launch(void* const* d_in, const int* in_sizes, int n_in,
                              void* d_out, int out_size, void* d_ws, size_t ws_size,
                              hipStream_t stream) {
  const float* x    = (const float*)d_in[0];
  const int*   ei   = (const int*)d_in[1];
  const float* W    = (const float*)d_in[2];
  const float* bias = (const float*)d_in[3];
  float* out = (float*)d_out;

  const int d_out_dim = in_sizes[3];             // 512
  const int d_in_dim  = in_sizes[2] / d_out_dim; // 512
  const int n_nodes   = in_sizes[0] / d_in_dim;  // 8192
  const int n_edges   = in_sizes[1] / 2;         // 262144
  const int words     = (n_nodes + 31) / 32;     // 256

  // workspace layout (bytes) — mask eliminated (adj lives in LDS now)
  char* ws = (char*)d_ws;
  size_t off = 0;
  int* deg       = (int*)(ws + off);      off += (size_t)n_nodes * 4;               // 32 KB
  float* dinv    = (float*)(ws + off);    off += (size_t)(n_nodes + 1) * 4;         // 32 KB + pad
  unsigned short* ell = (unsigned short*)(ws + off); off += (size_t)n_nodes * ELL_STRIDE * 2; // 2 MB
  unsigned short* xb  = (unsigned short*)(ws + off); off += (size_t)n_nodes * d_in_dim * 2;   // 8 MB
  unsigned short* Wt  = (unsigned short*)(ws + off); off += (size_t)d_in_dim * d_out_dim * 2; // 512 KB
  unsigned short* Hs  = (unsigned short*)(ws + off);
  off += (size_t)(n_nodes + 1) * d_out_dim * 2;  // 8 MB + pad row

  adj_ell_kernel<<<n_nodes / 64, 512, 0, stream>>>(ei, ell, deg, dinv,
                                                   n_nodes, n_edges, words);

  const int n4 = n_nodes * d_in_dim / 4;
  const int cast_blocks = (n4 + 255) / 256;                   // 4096
  const int tr_blocks = (d_in_dim / 32) * (d_out_dim / 32);   // 256
  prep_kernel<<<cast_blocks + tr_blocks + 1, 256, 0, stream>>>(
      x, xb, n4, W, Wt, d_in_dim, d_out_dim, Hs, dinv, n_nodes,
      cast_blocks, tr_blocks);

  const int nbx = d_out_dim / 128;                            // 4
  const int nbx_sh = 31 - __builtin_clz(nbx);                 // 2
  gemm_kernel<<<nbx * (n_nodes / 128), 256, 0, stream>>>(
      xb, Wt, Hs, n_nodes, d_out_dim, d_in_dim, nbx_sh);

  spmm_kernel<<<n_nodes / 4, 256, 0, stream>>>(ell, deg, dinv, Hs, bias, out,
                                               n_nodes, d_out_dim);
}

// Round 8
// 155.992 us; speedup vs baseline: 1.3207x; 1.3207x over previous
//
#include <hip/hip_runtime.h>
#include <hip/hip_bf16.h>

// ---------------------------------------------------------------------------
// GCN layer: out = D^{-1/2} (A_set + I) D^{-1/2} @ (x @ W) + bias
// Pipeline (4 dispatches):
//   memset mask (8MB)
//   fused_front: [build_adj atomicOr bitmask | cast x->bf16 | transpose W |
//                 pads]   (r7 lesson: LDS-bitmask-per-block adjacency = 95us
//                 — 128 blocks, 1 block/CU, redundant full edge scans; the
//                 device-atomic path ~48us total is the better structure)
//   fused_mid: [gemm 128x128 MFMA BK=64 (XOR-swizzled B) | build_ell]
//   spmm: QUARTER-D x LONG-LOOP — the untried cell of the shape matrix.
//     Ledger: full-D long-loop (r2/r6/r7, incl. explicit prefetch-8): ~45us,
//     L3-BW-bound (8.4MB > 4MB L2, 540MB gather at ~12TB/s). Quarter-D
//     short-loop (r5): L2-resident (FETCH 17MB) but 17-iter loops + 4x
//     staging = 48us. Half-D long-loop (r4): 4.2MB thrashes L2 (FETCH 80MB).
//     This round: quarter-D (2.1MB/XCD, resident per r5) + wave-per-node
//     long loop (66 iters, staging amortized per r2) + NT out stores so the
//     16MB output stream doesn't evict the resident Hs quarter.
// ---------------------------------------------------------------------------

#define ELL_STRIDE 128

typedef __attribute__((ext_vector_type(8))) short bf16x8;
typedef __attribute__((ext_vector_type(4))) float f32x4;
typedef __attribute__((ext_vector_type(2))) float f32x2;

__device__ __forceinline__ unsigned short f2bf(float f) {
  unsigned u = __float_as_uint(f);
  u = (u + 0x7fff + ((u >> 16) & 1)) >> 16;  // RNE
  return (unsigned short)u;
}
__device__ __forceinline__ float bflo(unsigned u) {
  return __uint_as_float(u << 16);
}
__device__ __forceinline__ float bfhi(unsigned u) {
  return __uint_as_float(u & 0xffff0000u);
}

// ---- fused front-end:
// [0,eb): build_adj  [eb,eb+cb): cast  [..+tb): transpose  [last]: pad row
__global__ __launch_bounds__(256) void fused_front_kernel(
    const int* __restrict__ ei, unsigned* __restrict__ mask, int n_edges,
    int words,
    const float* __restrict__ x, unsigned short* __restrict__ xb, int n4,
    const float* __restrict__ W, unsigned short* __restrict__ Wt, int K, int N,
    unsigned short* __restrict__ Hs, float* __restrict__ dinv, int n_nodes,
    int edge_blocks, int cast_blocks, int tr_blocks) {
  const int bid = blockIdx.x;
  if (bid < edge_blocks) {
    const int e = bid * 256 + threadIdx.x;
    if (e < n_edges) {
      const int u = ei[e];
      const int v = ei[e + n_edges];
      // fire-and-forget: never use the return value
      atomicOr(&mask[(size_t)u * words + (v >> 5)], 1u << (v & 31));
      atomicOr(&mask[(size_t)v * words + (u >> 5)], 1u << (u & 31));
    }
    return;
  }
  if (bid < edge_blocks + cast_blocks) {
    const int t = (bid - edge_blocks) * 256 + threadIdx.x;
    if (t < n4) {
      float4 v = ((const float4*)x)[t];
      ushort4 o;
      o.x = f2bf(v.x); o.y = f2bf(v.y); o.z = f2bf(v.z); o.w = f2bf(v.w);
      ((ushort4*)xb)[t] = o;
    }
    return;
  }
  if (bid < edge_blocks + cast_blocks + tr_blocks) {
    // transpose+cast: W[K][N] fp32 -> Wt[N][K] bf16, 32x32 tiles
    __shared__ float tile[32][33];
    const int b = bid - edge_blocks - cast_blocks;
    const int bx = b & ((N >> 5) - 1);
    const int by = b >> (31 - __builtin_clz(N >> 5));
    const int tx = threadIdx.x & 31;
    const int ty = threadIdx.x >> 5;  // 0..7
#pragma unroll
    for (int r = 0; r < 4; ++r)
      tile[ty + 8 * r][tx] = W[(size_t)(by * 32 + ty + 8 * r) * N + bx * 32 + tx];
    __syncthreads();
#pragma unroll
    for (int r = 0; r < 4; ++r)
      Wt[(size_t)(bx * 32 + ty + 8 * r) * K + by * 32 + tx] =
          f2bf(tile[tx][ty + 8 * r]);
    return;
  }
  // zero the ELL pad row Hs[n_nodes][:] and its scale dinv[n_nodes]
  {
    const int t = threadIdx.x;
    if (t < (N >> 1)) ((unsigned*)(Hs + (size_t)n_nodes * N))[t] = 0;
    if (t == 0) dinv[n_nodes] = 0.f;
  }
}

// ---- fused mid: [0,gb): gemm 128x128 BK=64   [gb..): build_ell (wave/node)
__global__ __launch_bounds__(256) void fused_mid_kernel(
    const unsigned short* __restrict__ xb,  // [M][K] bf16
    const unsigned short* __restrict__ Wt,  // [N][K] bf16
    unsigned short* __restrict__ Hs,        // [M+1][N] bf16 (unscaled)
    const unsigned* __restrict__ mask, unsigned short* __restrict__ ell,
    int* __restrict__ deg, float* __restrict__ dinv,
    int M, int N, int K, int words, int gemm_blocks, int nbx_sh) {
  // 128x128 tile, BK=64, 4 waves 2x2, each wave 64x64 out (4x4 16x16x32).
  // A slot s (0..1023): row=s&127, kc=s>>7 -> xb[m0+row][k0+kc*8]
  // B slot s (0..1023): bn=s>>3, bk=(s&7)^(bn&7)  (XOR source pre-swizzle:
  //   stride-128B fragment read spans all 8 bank-quads; source swizzled
  //   because global_load_lds forces a linear LDS dest).
  __shared__ unsigned short As[1024 * 8];
  __shared__ unsigned short Bs[1024 * 8];

  const int tid = threadIdx.x;
  const int bid = blockIdx.x;

  if (bid < gemm_blocks) {
    const int wave = tid >> 6;
    const int lane = tid & 63;
    const int q = lane >> 4;   // quad
    const int c = lane & 15;
    const int bx = bid & ((1 << nbx_sh) - 1);
    const int by = bid >> nbx_sh;
    const int m0 = by * 128;
    const int n0 = bx * 128;
    const int wr = wave >> 1, wc = wave & 1;

    f32x4 acc[4][4] = {};

    for (int k0 = 0; k0 < K; k0 += 64) {
#pragma unroll
      for (int t = 0; t < 4; ++t) {
        const int sbase = t * 256 + wave * 64;
        const int s = sbase + lane;
        const unsigned short* g =
            xb + (size_t)(m0 + (s & 127)) * K + k0 + (s >> 7) * 8;
        __builtin_amdgcn_global_load_lds(
            (const __attribute__((address_space(1))) void*)g,
            (__attribute__((address_space(3))) void*)(As + sbase * 8), 16, 0, 0);
      }
#pragma unroll
      for (int t = 0; t < 4; ++t) {
        const int sbase = t * 256 + wave * 64;
        const int s = sbase + lane;
        const int bn = s >> 3;
        const int bk = (s & 7) ^ (bn & 7);  // XOR-swizzled source (same 128B seg)
        const unsigned short* g =
            Wt + (size_t)(n0 + bn) * K + k0 + bk * 8;
        __builtin_amdgcn_global_load_lds(
            (const __attribute__((address_space(1))) void*)g,
            (__attribute__((address_space(3))) void*)(Bs + sbase * 8), 16, 0, 0);
      }
      __syncthreads();

#pragma unroll
      for (int kk = 0; kk < 2; ++kk) {
        bf16x8 a[4], b[4];
#pragma unroll
        for (int tm = 0; tm < 4; ++tm) {
          const int row = wr * 64 + tm * 16 + c;
          a[tm] = *(const bf16x8*)(As + (((kk * 4 + q) * 128) + row) * 8);
        }
#pragma unroll
        for (int tn = 0; tn < 4; ++tn) {
          const int n = wc * 64 + tn * 16 + c;
          b[tn] = *(const bf16x8*)(Bs + (n * 8 + ((kk * 4 + q) ^ (n & 7))) * 8);
        }
#pragma unroll
        for (int tm = 0; tm < 4; ++tm)
#pragma unroll
          for (int tn = 0; tn < 4; ++tn)
            acc[tm][tn] = __builtin_amdgcn_mfma_f32_16x16x32_bf16(
                a[tm], b[tn], acc[tm][tn], 0, 0, 0);
      }
      __syncthreads();
    }

    // C/D mapping: col=lane&15, row=quad*4+reg ; unscaled store
#pragma unroll
    for (int tm = 0; tm < 4; ++tm) {
#pragma unroll
      for (int r = 0; r < 4; ++r) {
        const int grow = m0 + wr * 64 + tm * 16 + q * 4 + r;
#pragma unroll
        for (int tn = 0; tn < 4; ++tn) {
          const int gcol = n0 + wc * 64 + tn * 16 + c;
          Hs[(size_t)grow * N + gcol] = f2bf(acc[tm][tn][r]);
        }
      }
    }
    return;
  }

  // ---- build_ell: one wave per node, popcount + lane prefix-scan.
  {
    const int wave = tid >> 6, lane = tid & 63;
    const int node = (bid - gemm_blocks) * 4 + wave;
    const unsigned* __restrict__ row = mask + (size_t)node * words;
    unsigned short* __restrict__ out = ell + (size_t)node * ELL_STRIDE;

    int running = 0;
    for (int r = 0; r < words; r += 64) {
      const int w = r + lane;
      unsigned bits = row[w];
      const int cnt = __popc(bits);
      int x = cnt;
#pragma unroll
      for (int d = 1; d < 64; d <<= 1) {
        int y = __shfl_up(x, d, 64);
        if (lane >= d) x += y;
      }
      int pos = running + x - cnt;
      while (bits) {
        const int b = __builtin_ctz(bits);
        bits &= bits - 1;
        if (pos < ELL_STRIDE) out[pos] = (unsigned short)((w << 5) + b);
        ++pos;
      }
      running += __shfl(x, 63, 64);
    }
    // self entry at [running], pads (index M -> dinv 0, zero row) after
    for (int p = running + lane; p < ELL_STRIDE; p += 64)
      out[p] = (unsigned short)(p == running ? node : M);
    if (lane == 0) {
      const int dd = running + 1;  // + self
      deg[node] = dd < ELL_STRIDE ? dd : ELL_STRIDE;
      dinv[node] = rsqrtf((float)running + 1.0f);
    }
  }
}

// ---- spmm: grid 4*(n/4) blocks; wave = one node, QUARTER of D, LONG loop.
// qt = bid&3: bid%8 -> XCD round-robin, so XCDs {k, k+4} serve quarter k&3
// -> per-XCD gather working set = 8192x128x2B = 2.1MB, L2-resident (r5
// proved residency at this size: FETCH 17MB). 64 lanes x 4B = one 256B
// quarter-row per iter, fully coalesced; ~66 iters/wave (r2 shape).
// (byte_offset, dinv_j) staged once per wave in LDS; each lane owns 2
// output cols -> no cross-lane reduce. NT out stores so the 16MB output
// stream doesn't evict the resident Hs quarter from L2.
__global__ __launch_bounds__(256) void spmm_kernel(
    const unsigned short* __restrict__ ell, const int* __restrict__ deg,
    const float* __restrict__ dinv, const unsigned short* __restrict__ Hs,
    const float* __restrict__ bias, float* __restrict__ out, int n, int D) {
  __shared__ uint2 ji[4][ELL_STRIDE];
  const int wave = threadIdx.x >> 6, lane = threadIdx.x & 63;
  const int bid = blockIdx.x;
  const int qt = bid & 3;               // quarter, XCD-pinned
  const int i = (bid >> 2) * 4 + wave;  // node
  const unsigned rowbytes = (unsigned)(D * 2);

  {  // stage (byte offset, dinv[j]) — 2 entries per lane; dinv 32KB -> L1
    const unsigned j0 = ell[(size_t)i * ELL_STRIDE + lane];
    const unsigned j1 = ell[(size_t)i * ELL_STRIDE + 64 + lane];
    ji[wave][lane] = make_uint2(j0 * rowbytes, __float_as_uint(dinv[j0]));
    ji[wave][64 + lane] = make_uint2(j1 * rowbytes, __float_as_uint(dinv[j1]));
  }
  const int d = deg[i];            // includes the self entry
  const float di = dinv[i];
  const int kmax = (d + 7) & ~7;   // ELL pads (dinv 0, zero row) cover tail

  // this wave reads bytes [qt*256, qt*256+256) of each row: 4B per lane
  const char* __restrict__ hb = (const char*)Hs + qt * 256 + lane * 4;
  float a0 = 0.f, a1 = 0.f;

#pragma unroll 8
  for (int k = 0; k < kmax; ++k) {
    const uint2 e = ji[wave][k];  // uniform addr -> LDS broadcast
    const float dj = __uint_as_float(e.y);
    const unsigned hv = *(const unsigned*)(hb + e.x);
    a0 += dj * bflo(hv);
    a1 += dj * bfhi(hv);
  }

  const int col = qt * (D >> 2) + lane * 2;
  const float2 b = *(const float2*)(bias + col);
  f32x2 o;
  o.x = di * a0 + b.x;
  o.y = di * a1 + b.y;
  __builtin_nontemporal_store(o, (f32x2*)(out + (size_t)i * D + col));
}

extern "C" void kernel_launch(void* const* d_in, const int* in_sizes, int n_in,
                              void* d_out, int out_size, void* d_ws, size_t ws_size,
                              hipStream_t stream) {
  const float* x    = (const float*)d_in[0];
  const int*   ei   = (const int*)d_in[1];
  const float* W    = (const float*)d_in[2];
  const float* bias = (const float*)d_in[3];
  float* out = (float*)d_out;

  const int d_out_dim = in_sizes[3];             // 512
  const int d_in_dim  = in_sizes[2] / d_out_dim; // 512
  const int n_nodes   = in_sizes[0] / d_in_dim;  // 8192
  const int n_edges   = in_sizes[1] / 2;         // 262144
  const int words     = (n_nodes + 31) / 32;     // 256

  // workspace layout (bytes)
  char* ws = (char*)d_ws;
  size_t off = 0;
  unsigned* mask = (unsigned*)(ws + off); off += (size_t)n_nodes * words * 4;       // 8 MB
  int* deg       = (int*)(ws + off);      off += (size_t)n_nodes * 4;               // 32 KB
  float* dinv    = (float*)(ws + off);    off += (size_t)(n_nodes + 1) * 4;         // 32 KB + pad
  unsigned short* ell = (unsigned short*)(ws + off); off += (size_t)n_nodes * ELL_STRIDE * 2; // 2 MB
  unsigned short* xb  = (unsigned short*)(ws + off); off += (size_t)n_nodes * d_in_dim * 2;   // 8 MB
  unsigned short* Wt  = (unsigned short*)(ws + off); off += (size_t)d_in_dim * d_out_dim * 2; // 512 KB
  unsigned short* Hs  = (unsigned short*)(ws + off);
  off += (size_t)(n_nodes + 1) * d_out_dim * 2;  // 8 MB + pad row

  hipMemsetAsync(mask, 0, (size_t)n_nodes * words * 4, stream);

  const int edge_blocks = (n_edges + 255) / 256;              // 1024
  const int n4 = n_nodes * d_in_dim / 4;
  const int cast_blocks = (n4 + 255) / 256;                   // 4096
  const int tr_blocks = (d_in_dim / 32) * (d_out_dim / 32);   // 256
  fused_front_kernel<<<edge_blocks + cast_blocks + tr_blocks + 1, 256, 0, stream>>>(
      ei, mask, n_edges, words, x, xb, n4, W, Wt, d_in_dim, d_out_dim,
      Hs, dinv, n_nodes, edge_blocks, cast_blocks, tr_blocks);

  const int nbx = d_out_dim / 128;                            // 4
  const int nbx_sh = 31 - __builtin_clz(nbx);                 // 2
  const int gemm_blocks = nbx * (n_nodes / 128);              // 256
  const int ell_blocks = n_nodes / 4;                         // 2048
  fused_mid_kernel<<<gemm_blocks + ell_blocks, 256, 0, stream>>>(
      xb, Wt, Hs, mask, ell, deg, dinv,
      n_nodes, d_out_dim, d_in_dim, words, gemm_blocks, nbx_sh);

  const int spmm_blocks = 4 * (n_nodes / 4);                  // 8192
  spmm_kernel<<<spmm_blocks, 256, 0, stream>>>(ell, deg, dinv, Hs, bias, out,
                                               n_nodes, d_out_dim);
}

// Round 9
// 150.677 us; speedup vs baseline: 1.3673x; 1.0353x over previous
//
#include <hip/hip_runtime.h>
#include <hip/hip_bf16.h>

// ---------------------------------------------------------------------------
// GCN layer: out = D^{-1/2} (A_set + I) D^{-1/2} @ (x @ W) + bias
// Pipeline (4 dispatches):
//   memset mask (8MB)
//   fused_front: [build_adj atomicOr bitmask | cast x->bf16 | transpose W |
//                 pads]
//   fused_mid: [gemm 64x128 MFMA BK=64 (XOR-swizzled B), 512 blocks so >=2
//               blocks/CU resident (256-block 128^2 grid was 1/CU -> no
//               inter-block latency hiding) | build_ell]
//   spmm: quarter-D x long-loop (r8 core, best measured) + LDS dinv table:
//     1024-thr blocks (16 waves = 16 node-quarters) stage dinv[8193] (32KB)
//     coalesced ONCE per block; ji built from scattered LDS reads (~2-way
//     conflicts = free) instead of 4.2M scattered GLOBAL loads (r8's hidden
//     staging tax). LDS 49KB -> 2 blocks/CU = 32 waves = full occupancy.
//   Ledger: spmm shape full-D ~40-45 (L3-BW ~13TB/s), half-D 47 (L2 thrash
//     FETCH 80MB), quarter-D short-loop 48 (staging x4), quarter-D long-loop
//     (r8) ~38 best; adjacency-in-LDS 95us (r7, rejected); harness re-poison
//     fill ~46us sits inside the timed window -> kernel budget ~110us.
// ---------------------------------------------------------------------------

#define ELL_STRIDE 128

typedef __attribute__((ext_vector_type(8))) short bf16x8;
typedef __attribute__((ext_vector_type(4))) float f32x4;
typedef __attribute__((ext_vector_type(2))) float f32x2;

__device__ __forceinline__ unsigned short f2bf(float f) {
  unsigned u = __float_as_uint(f);
  u = (u + 0x7fff + ((u >> 16) & 1)) >> 16;  // RNE
  return (unsigned short)u;
}
__device__ __forceinline__ float bflo(unsigned u) {
  return __uint_as_float(u << 16);
}
__device__ __forceinline__ float bfhi(unsigned u) {
  return __uint_as_float(u & 0xffff0000u);
}

// ---- fused front-end:
// [0,eb): build_adj  [eb,eb+cb): cast  [..+tb): transpose  [last]: pad row
__global__ __launch_bounds__(256) void fused_front_kernel(
    const int* __restrict__ ei, unsigned* __restrict__ mask, int n_edges,
    int words,
    const float* __restrict__ x, unsigned short* __restrict__ xb, int n4,
    const float* __restrict__ W, unsigned short* __restrict__ Wt, int K, int N,
    unsigned short* __restrict__ Hs, float* __restrict__ dinv, int n_nodes,
    int edge_blocks, int cast_blocks, int tr_blocks) {
  const int bid = blockIdx.x;
  if (bid < edge_blocks) {
    const int e = bid * 256 + threadIdx.x;
    if (e < n_edges) {
      const int u = ei[e];
      const int v = ei[e + n_edges];
      // fire-and-forget: never use the return value
      atomicOr(&mask[(size_t)u * words + (v >> 5)], 1u << (v & 31));
      atomicOr(&mask[(size_t)v * words + (u >> 5)], 1u << (u & 31));
    }
    return;
  }
  if (bid < edge_blocks + cast_blocks) {
    const int t = (bid - edge_blocks) * 256 + threadIdx.x;
    if (t < n4) {
      float4 v = ((const float4*)x)[t];
      ushort4 o;
      o.x = f2bf(v.x); o.y = f2bf(v.y); o.z = f2bf(v.z); o.w = f2bf(v.w);
      ((ushort4*)xb)[t] = o;
    }
    return;
  }
  if (bid < edge_blocks + cast_blocks + tr_blocks) {
    // transpose+cast: W[K][N] fp32 -> Wt[N][K] bf16, 32x32 tiles
    __shared__ float tile[32][33];
    const int b = bid - edge_blocks - cast_blocks;
    const int bx = b & ((N >> 5) - 1);
    const int by = b >> (31 - __builtin_clz(N >> 5));
    const int tx = threadIdx.x & 31;
    const int ty = threadIdx.x >> 5;  // 0..7
#pragma unroll
    for (int r = 0; r < 4; ++r)
      tile[ty + 8 * r][tx] = W[(size_t)(by * 32 + ty + 8 * r) * N + bx * 32 + tx];
    __syncthreads();
#pragma unroll
    for (int r = 0; r < 4; ++r)
      Wt[(size_t)(bx * 32 + ty + 8 * r) * K + by * 32 + tx] =
          f2bf(tile[tx][ty + 8 * r]);
    return;
  }
  // zero the ELL pad row Hs[n_nodes][:] and its scale dinv[n_nodes]
  {
    const int t = threadIdx.x;
    if (t < (N >> 1)) ((unsigned*)(Hs + (size_t)n_nodes * N))[t] = 0;
    if (t == 0) dinv[n_nodes] = 0.f;
  }
}

// ---- fused mid: [0,gb): gemm 64x128 BK=64   [gb..): build_ell (wave/node)
__global__ __launch_bounds__(256) void fused_mid_kernel(
    const unsigned short* __restrict__ xb,  // [M][K] bf16
    const unsigned short* __restrict__ Wt,  // [N][K] bf16
    unsigned short* __restrict__ Hs,        // [M+1][N] bf16 (unscaled)
    const unsigned* __restrict__ mask, unsigned short* __restrict__ ell,
    int* __restrict__ deg, float* __restrict__ dinv,
    int M, int N, int K, int words, int gemm_blocks, int nbx_sh) {
  // 64x128 tile (BM=64, BN=128), BK=64, 4 waves 2x2, wave tile 32x64
  // (acc[2][4] of 16x16x32). 512 blocks -> 2+ blocks/CU resident (the
  // 128^2 grid was exactly 1/CU: no inter-block latency hiding).
  // A slot s (0..511): row=s&63, kc=s>>6 -> xb[m0+row][k0+kc*8]
  // B slot s (0..1023): bn=s>>3, bk=(s&7)^(bn&7)  (XOR source pre-swizzle:
  //   stride-128B fragment read spans all 8 bank-quads; source swizzled
  //   because global_load_lds forces a linear LDS dest).
  __shared__ unsigned short As[512 * 8];
  __shared__ unsigned short Bs[1024 * 8];

  const int tid = threadIdx.x;
  const int bid = blockIdx.x;

  if (bid < gemm_blocks) {
    const int wave = tid >> 6;
    const int lane = tid & 63;
    const int q = lane >> 4;   // quad
    const int c = lane & 15;
    const int bx = bid & ((1 << nbx_sh) - 1);
    const int by = bid >> nbx_sh;
    const int m0 = by * 64;
    const int n0 = bx * 128;
    const int wr = wave >> 1, wc = wave & 1;

    f32x4 acc[2][4] = {};

    for (int k0 = 0; k0 < K; k0 += 64) {
#pragma unroll
      for (int t = 0; t < 2; ++t) {
        const int sbase = t * 256 + wave * 64;
        const int s = sbase + lane;
        const unsigned short* g =
            xb + (size_t)(m0 + (s & 63)) * K + k0 + (s >> 6) * 8;
        __builtin_amdgcn_global_load_lds(
            (const __attribute__((address_space(1))) void*)g,
            (__attribute__((address_space(3))) void*)(As + sbase * 8), 16, 0, 0);
      }
#pragma unroll
      for (int t = 0; t < 4; ++t) {
        const int sbase = t * 256 + wave * 64;
        const int s = sbase + lane;
        const int bn = s >> 3;
        const int bk = (s & 7) ^ (bn & 7);  // XOR-swizzled source (same 128B seg)
        const unsigned short* g =
            Wt + (size_t)(n0 + bn) * K + k0 + bk * 8;
        __builtin_amdgcn_global_load_lds(
            (const __attribute__((address_space(1))) void*)g,
            (__attribute__((address_space(3))) void*)(Bs + sbase * 8), 16, 0, 0);
      }
      __syncthreads();

#pragma unroll
      for (int kk = 0; kk < 2; ++kk) {
        bf16x8 a[2], b[4];
#pragma unroll
        for (int tm = 0; tm < 2; ++tm) {
          const int row = wr * 32 + tm * 16 + c;
          a[tm] = *(const bf16x8*)(As + (((kk * 4 + q) * 64) + row) * 8);
        }
#pragma unroll
        for (int tn = 0; tn < 4; ++tn) {
          const int n = wc * 64 + tn * 16 + c;
          b[tn] = *(const bf16x8*)(Bs + (n * 8 + ((kk * 4 + q) ^ (n & 7))) * 8);
        }
#pragma unroll
        for (int tm = 0; tm < 2; ++tm)
#pragma unroll
          for (int tn = 0; tn < 4; ++tn)
            acc[tm][tn] = __builtin_amdgcn_mfma_f32_16x16x32_bf16(
                a[tm], b[tn], acc[tm][tn], 0, 0, 0);
      }
      __syncthreads();
    }

    // C/D mapping: col=lane&15, row=quad*4+reg ; unscaled store
#pragma unroll
    for (int tm = 0; tm < 2; ++tm) {
#pragma unroll
      for (int r = 0; r < 4; ++r) {
        const int grow = m0 + wr * 32 + tm * 16 + q * 4 + r;
#pragma unroll
        for (int tn = 0; tn < 4; ++tn) {
          const int gcol = n0 + wc * 64 + tn * 16 + c;
          Hs[(size_t)grow * N + gcol] = f2bf(acc[tm][tn][r]);
        }
      }
    }
    return;
  }

  // ---- build_ell: one wave per node, popcount + lane prefix-scan.
  {
    const int wave = tid >> 6, lane = tid & 63;
    const int node = (bid - gemm_blocks) * 4 + wave;
    const unsigned* __restrict__ row = mask + (size_t)node * words;
    unsigned short* __restrict__ out = ell + (size_t)node * ELL_STRIDE;

    int running = 0;
    for (int r = 0; r < words; r += 64) {
      const int w = r + lane;
      unsigned bits = row[w];
      const int cnt = __popc(bits);
      int x = cnt;
#pragma unroll
      for (int d = 1; d < 64; d <<= 1) {
        int y = __shfl_up(x, d, 64);
        if (lane >= d) x += y;
      }
      int pos = running + x - cnt;
      while (bits) {
        const int b = __builtin_ctz(bits);
        bits &= bits - 1;
        if (pos < ELL_STRIDE) out[pos] = (unsigned short)((w << 5) + b);
        ++pos;
      }
      running += __shfl(x, 63, 64);
    }
    // self entry at [running], pads (index M -> dinv 0, zero row) after
    for (int p = running + lane; p < ELL_STRIDE; p += 64)
      out[p] = (unsigned short)(p == running ? node : M);
    if (lane == 0) {
      const int dd = running + 1;  // + self
      deg[node] = dd < ELL_STRIDE ? dd : ELL_STRIDE;
      dinv[node] = rsqrtf((float)running + 1.0f);
    }
  }
}

// ---- spmm: grid 4*(n/16) blocks x 1024 thr; wave = one node-quarter.
// qt = bid&3 (bid%8 XCD round-robin -> quarter k on XCDs {k,k+4}, 2.1MB
// L2-resident working set). Block stages dinv[8193] (32KB) into LDS ONCE,
// coalesced; ji = (byte offset, dinv_j) then built from scattered LDS
// reads (~2-way bank alias = free) -- replaces r8's 4.2M scattered GLOBAL
// dinv loads (the hidden staging tax). 64 lanes x 4B = one 256B quarter
// row per iter, ~66 iters/wave. LDS 49KB -> 2 blocks/CU = 32 waves (full).
__global__ __launch_bounds__(1024) void spmm_kernel(
    const unsigned short* __restrict__ ell, const int* __restrict__ deg,
    const float* __restrict__ dinv, const unsigned short* __restrict__ Hs,
    const float* __restrict__ bias, float* __restrict__ out, int n, int D) {
  __shared__ float sdinv[8193];
  __shared__ uint2 ji[16][ELL_STRIDE];
  const int tid = threadIdx.x;
  const int wave = tid >> 6, lane = tid & 63;
  const int bid = blockIdx.x;
  const int qt = bid & 3;                     // quarter, XCD-pinned
  const int i = (bid >> 2) * 16 + wave;       // node (n divisible by 16)
  const unsigned rowbytes = (unsigned)(D * 2);

  for (int t = tid; t < n + 1; t += 1024) sdinv[t] = dinv[t];
  __syncthreads();

  {  // stage (byte offset, dinv[j]) — scattered LDS lookups, cheap
    const unsigned j0 = ell[(size_t)i * ELL_STRIDE + lane];
    const unsigned j1 = ell[(size_t)i * ELL_STRIDE + 64 + lane];
    ji[wave][lane] = make_uint2(j0 * rowbytes, __float_as_uint(sdinv[j0]));
    ji[wave][64 + lane] = make_uint2(j1 * rowbytes, __float_as_uint(sdinv[j1]));
  }
  const int d = deg[i];            // includes the self entry
  const float di = sdinv[i];
  const int kmax = (d + 7) & ~7;   // ELL pads (dinv 0, zero row) cover tail

  // this wave reads bytes [qt*256, qt*256+256) of each row: 4B per lane
  const char* __restrict__ hb = (const char*)Hs + qt * 256 + lane * 4;
  float a0 = 0.f, a1 = 0.f;

#pragma unroll 8
  for (int k = 0; k < kmax; ++k) {
    const uint2 e = ji[wave][k];  // uniform addr -> LDS broadcast
    const float dj = __uint_as_float(e.y);
    const unsigned hv = *(const unsigned*)(hb + e.x);
    a0 += dj * bflo(hv);
    a1 += dj * bfhi(hv);
  }

  const int col = qt * (D >> 2) + lane * 2;
  const float2 b = *(const float2*)(bias + col);
  f32x2 o;
  o.x = di * a0 + b.x;
  o.y = di * a1 + b.y;
  __builtin_nontemporal_store(o, (f32x2*)(out + (size_t)i * D + col));
}

extern "C" void kernel_launch(void* const* d_in, const int* in_sizes, int n_in,
                              void* d_out, int out_size, void* d_ws, size_t ws_size,
                              hipStream_t stream) {
  const float* x    = (const float*)d_in[0];
  const int*   ei   = (const int*)d_in[1];
  const float* W    = (const float*)d_in[2];
  const float* bias = (const float*)d_in[3];
  float* out = (float*)d_out;

  const int d_out_dim = in_sizes[3];             // 512
  const int d_in_dim  = in_sizes[2] / d_out_dim; // 512
  const int n_nodes   = in_sizes[0] / d_in_dim;  // 8192
  const int n_edges   = in_sizes[1] / 2;         // 262144
  const int words     = (n_nodes + 31) / 32;     // 256

  // workspace layout (bytes)
  char* ws = (char*)d_ws;
  size_t off = 0;
  unsigned* mask = (unsigned*)(ws + off); off += (size_t)n_nodes * words * 4;       // 8 MB
  int* deg       = (int*)(ws + off);      off += (size_t)n_nodes * 4;               // 32 KB
  float* dinv    = (float*)(ws + off);    off += (size_t)(n_nodes + 1) * 4;         // 32 KB + pad
  unsigned short* ell = (unsigned short*)(ws + off); off += (size_t)n_nodes * ELL_STRIDE * 2; // 2 MB
  unsigned short* xb  = (unsigned short*)(ws + off); off += (size_t)n_nodes * d_in_dim * 2;   // 8 MB
  unsigned short* Wt  = (unsigned short*)(ws + off); off += (size_t)d_in_dim * d_out_dim * 2; // 512 KB
  unsigned short* Hs  = (unsigned short*)(ws + off);
  off += (size_t)(n_nodes + 1) * d_out_dim * 2;  // 8 MB + pad row

  hipMemsetAsync(mask, 0, (size_t)n_nodes * words * 4, stream);

  const int edge_blocks = (n_edges + 255) / 256;              // 1024
  const int n4 = n_nodes * d_in_dim / 4;
  const int cast_blocks = (n4 + 255) / 256;                   // 4096
  const int tr_blocks = (d_in_dim / 32) * (d_out_dim / 32);   // 256
  fused_front_kernel<<<edge_blocks + cast_blocks + tr_blocks + 1, 256, 0, stream>>>(
      ei, mask, n_edges, words, x, xb, n4, W, Wt, d_in_dim, d_out_dim,
      Hs, dinv, n_nodes, edge_blocks, cast_blocks, tr_blocks);

  const int nbx = d_out_dim / 128;                            // 4
  const int nbx_sh = 31 - __builtin_clz(nbx);                 // 2
  const int gemm_blocks = nbx * (n_nodes / 64);               // 512
  const int ell_blocks = n_nodes / 4;                         // 2048
  fused_mid_kernel<<<gemm_blocks + ell_blocks, 256, 0, stream>>>(
      xb, Wt, Hs, mask, ell, deg, dinv,
      n_nodes, d_out_dim, d_in_dim, words, gemm_blocks, nbx_sh);

  const int spmm_blocks = 4 * (n_nodes / 16);                 // 2048
  spmm_kernel<<<spmm_blocks, 1024, 0, stream>>>(ell, deg, dinv, Hs, bias, out,
                                                n_nodes, d_out_dim);
}